// Round 15
// baseline (189.459 us; speedup 1.0000x reference)
//
#include <hip/hip_runtime.h>
#include <hip/hip_bf16.h>

typedef __bf16 bf16x8 __attribute__((ext_vector_type(8)));
typedef __bf16 bf16x4 __attribute__((ext_vector_type(4)));
typedef float  f32x4  __attribute__((ext_vector_type(4)));
typedef float  f32x16 __attribute__((ext_vector_type(16)));

#define DIM 1024
#define NHEAD 16
#define HD 64
#define BATCH 4
#define SEQ 2048
#define MROWS (BATCH * SEQ)        // 8192
#define NX (MROWS * DIM)           // 8388608
#define NQW (3 * DIM * DIM)        // 3145728
#define NPW (DIM * DIM)            // 1048576

// Q pre-scale: (1/sqrt(64)) * log2(e), so softmax uses exp2 directly.
#define QSC (0.125f * 1.44269504088896340736f)

// ---------------- fp32 -> bf16 convert (all three tensors, one launch) ----
__global__ void cvt_all(const float* __restrict__ x, const float* __restrict__ wq,
                        const float* __restrict__ wp, __bf16* __restrict__ xb,
                        __bf16* __restrict__ wqb, __bf16* __restrict__ wpb) {
    const int total = (NX + NQW + NPW) / 4;
    int stride = gridDim.x * blockDim.x;
    for (int c = blockIdx.x * blockDim.x + threadIdx.x; c < total; c += stride) {
        int i = c * 4;
        const float* src; __bf16* dst; int off;
        if (i < NX)            { src = x;  dst = xb;  off = i; }
        else if (i < NX + NQW) { src = wq; dst = wqb; off = i - NX; }
        else                   { src = wp; dst = wpb; off = i - NX - NQW; }
        float4 v = *(const float4*)&src[off];
        bf16x4 o = { (__bf16)v.x, (__bf16)v.y, (__bf16)v.z, (__bf16)v.w };
        *(bf16x4*)&dst[off] = o;
    }
}

// ---------------- GEMM1: qkv = x @ w_qkv.T, scatter to Q/K/Vt -------------
// R9-verified 2-barrier structure + T1 XCD swizzle: 1D grid 1536, each XCD
// owns 8 contiguous m-panels (A L2-resident: 2MB A + 6MB W per XCD).
__global__ __launch_bounds__(256) void gemm_qkv(
    const __bf16* __restrict__ X, const __bf16* __restrict__ W,
    __bf16* __restrict__ Qo, __bf16* __restrict__ Ko, __bf16* __restrict__ Vt) {
    __shared__ __align__(16) __bf16 As[128][72];
    __shared__ __align__(16) __bf16 Bs[128][72];
    // XCD swizzle: hw XCD = lin%8; XCD x gets swz in [x*192, (x+1)*192) ->
    // m-panels [x*8, x*8+8), n fast. 1536 % 8 == 0 -> bijective.
    const int lin = blockIdx.x;
    const int swz = (lin & 7) * 192 + (lin >> 3);
    const int m0 = (swz / 24) * 128, n0 = (swz % 24) * 128;
    const int tid = threadIdx.x;
    const int w = tid >> 6, lane = tid & 63;
    const int wm = w >> 1, wn = w & 1;
    const int lr = lane & 15, lg = lane >> 4;
    const int ldr = tid >> 3;          // 0..31
    const int ldc = (tid & 7) * 8;     // 0..56

    f32x4 acc[4][4];
    const f32x4 z = {0.f, 0.f, 0.f, 0.f};
#pragma unroll
    for (int i = 0; i < 4; ++i)
#pragma unroll
        for (int j = 0; j < 4; ++j) acc[i][j] = z;

    for (int kt = 0; kt < DIM; kt += 64) {
#pragma unroll
        for (int rr = 0; rr < 128; rr += 32) {
            *(bf16x8*)&As[ldr + rr][ldc] =
                *(const bf16x8*)&X[(size_t)(m0 + ldr + rr) * DIM + kt + ldc];
            *(bf16x8*)&Bs[ldr + rr][ldc] =
                *(const bf16x8*)&W[(size_t)(n0 + ldr + rr) * DIM + kt + ldc];
        }
        __syncthreads();
#pragma unroll
        for (int kk = 0; kk < 2; ++kk) {
            bf16x8 a[4], b[4];
#pragma unroll
            for (int i = 0; i < 4; ++i)
                a[i] = *(const bf16x8*)&As[wm * 64 + i * 16 + lr][kk * 32 + lg * 8];
#pragma unroll
            for (int j = 0; j < 4; ++j)
                b[j] = *(const bf16x8*)&Bs[wn * 64 + j * 16 + lr][kk * 32 + lg * 8];
#pragma unroll
            for (int i = 0; i < 4; ++i)
#pragma unroll
                for (int j = 0; j < 4; ++j)
                    acc[i][j] = __builtin_amdgcn_mfma_f32_16x16x32_bf16(a[i], b[j], acc[i][j], 0, 0, 0);
        }
        __syncthreads();
    }

    // epilogue: n -> (t, h, d); t uniform per block (128 | 1024)
    const int t = n0 >> 10;
    if (t < 2) {
        __bf16* dst = (t == 0) ? Qo : Ko;
        const float sc = (t == 0) ? QSC : 1.0f;
#pragma unroll
        for (int i = 0; i < 4; ++i) {
#pragma unroll
            for (int j = 0; j < 4; ++j) {
                int n = n0 + wn * 64 + j * 16 + lr;
                int rem = n & 1023, h = rem >> 6, d = rem & 63;
#pragma unroll
                for (int rr = 0; rr < 4; ++rr) {
                    int m = m0 + wm * 64 + i * 16 + lg * 4 + rr;
                    int b = m >> 11, pos = m & 2047;
                    dst[(((size_t)b * NHEAD + h) * SEQ + pos) * HD + d] =
                        (__bf16)(acc[i][j][rr] * sc);
                }
            }
        }
    } else {
        // V: transposed store, vectorized bf16x4 (rr -> consecutive pos)
#pragma unroll
        for (int i = 0; i < 4; ++i) {
#pragma unroll
            for (int j = 0; j < 4; ++j) {
                int n = n0 + wn * 64 + j * 16 + lr;
                int rem = n & 1023, h = rem >> 6, d = rem & 63;
                int m = m0 + wm * 64 + i * 16 + lg * 4;
                int b = m >> 11, pos = m & 2047;
                bf16x4 v4 = { (__bf16)acc[i][j][0], (__bf16)acc[i][j][1],
                              (__bf16)acc[i][j][2], (__bf16)acc[i][j][3] };
                *(bf16x4*)&Vt[(((size_t)b * NHEAD + h) * HD + d) * SEQ + pos] = v4;
            }
        }
    }
}

// pack two f32 -> one u32 of 2 bf16 (lo = a, hi = b); scalar casts — the
// compiler fuses these to v_cvt_pk_bf16_f32 itself (T12/m240).
__device__ __forceinline__ unsigned pk2(float a, float b) {
    __bf16 x = (__bf16)a, y = (__bf16)b;
    unsigned short xu = __builtin_bit_cast(unsigned short, x);
    unsigned short yu = __builtin_bit_cast(unsigned short, y);
    return (unsigned)xu | ((unsigned)yu << 16);
}

// ---------------- flash attention, KVBLK=128 LDS-staged K/V ---------------
// (R12-verified at 88.4 µs: 512 blocks XCD-swizzled, 8 waves x 32 q-rows,
// 128 k-rows staged per barrier — two 64-row compute halves per iteration,
// 16 iterations, 1 barrier each. Double-buffered 32KB buffers.)
// LDS layout per buffer (16B chunks):
//   K region [0,16384):     chunk(sub,row) at sub*2048 + (row*16 ^ sub*16),
//                           sub = d-octet 0..7, row 0..127
//   V region [16384,32768): chunk(j,d) at 16384 + j*1024 + (d*16 ^ (j&7)*16),
//                           j = k-octet 0..15, d 0..63
// XOR applied identically on write and read (bijective per region).
__global__ __launch_bounds__(512) void flash_attn10(
    const __bf16* __restrict__ Q, const __bf16* __restrict__ K,
    const __bf16* __restrict__ Vt, __bf16* __restrict__ AO) {
    __shared__ __align__(16) char ldsbuf[2][32768];
    const int L = blockIdx.x;                 // 0..511
    const int xcd = L & 7;                    // hw XCD = id % 8
    const int mloc = L >> 3;                  // 0..63 within XCD
    const int bh = xcd * 8 + (mloc >> 3);     // 8 heads per XCD
    const int qt = mloc & 7;                  // q-tile (256 rows), fast index
    const int tid = threadIdx.x;              // 0..511
    const int w = tid >> 6, lane = tid & 63;  // w: 0..7
    const int l31 = lane & 31, hi = lane >> 5;
    const int qb = qt * 256 + w * 32;
    const size_t kvQ = (size_t)bh * SEQ * HD;
    const size_t kvV = (size_t)bh * HD * SEQ;

    // Q B-frags: qf[ks][j] = Q[qb + l31][ks*16 + hi*8 + j]  (one-time gather)
    bf16x8 qf[4];
#pragma unroll
    for (int ks = 0; ks < 4; ++ks)
        qf[ks] = *(const bf16x8*)&Q[kvQ + (size_t)(qb + l31) * HD + ks * 16 + hi * 8];

    bf16x8 ones;
#pragma unroll
    for (int j = 0; j < 8; ++j) ones[j] = (__bf16)1.0f;

    f32x16 o0 = {}, o1 = {}, lac = {};

    const char* gK = (const char*)K + kvQ * 2 + tid * 16;
    const char* gV = (const char*)Vt + kvV * 2 + (size_t)(tid >> 4) * 4096 + (tid & 15) * 16;
    const int dK = (tid & 7) * 2048 + (((tid >> 3) * 16) ^ ((tid & 7) * 16));
    const int dV = 16384 + (tid & 15) * 1024 + (((tid >> 4) * 16) ^ (((tid & 15) & 7) * 16));

    int kxo[4], vxo[4];
#pragma unroll
    for (int i = 0; i < 4; ++i) {
        kxo[i] = i * 4096 + hi * 2048 + ((l31 * 16) ^ ((2 * i + hi) << 4));
        vxo[i] = 16384 + i * 2048 + hi * 1024 + ((l31 * 16) ^ ((2 * i + hi) << 4));
    }

#define PV_STEP(UARR, C, CT, VH)                                                \
    {                                                                           \
        unsigned w0_ = UARR[4 * C], w1_ = UARR[4 * C + 1];                      \
        unsigned w2_ = UARR[4 * C + 2], w3_ = UARR[4 * C + 3];                  \
        asm("v_permlane32_swap_b32 %0, %1" : "+v"(w0_), "+v"(w2_));             \
        asm("v_permlane32_swap_b32 %0, %1" : "+v"(w1_), "+v"(w3_));             \
        union { unsigned q[4]; bf16x8 v; } af_;                                 \
        af_.q[0] = w0_; af_.q[1] = w1_; af_.q[2] = w2_; af_.q[3] = w3_;         \
        bf16x8 v0f = *(const bf16x8*)(ldb + vxo[CT] + (VH));                    \
        bf16x8 v1f = *(const bf16x8*)(ldb + vxo[CT] + (VH) + 512);              \
        o0  = __builtin_amdgcn_mfma_f32_32x32x16_bf16(af_.v, v0f, o0, 0, 0, 0); \
        o1  = __builtin_amdgcn_mfma_f32_32x32x16_bf16(af_.v, v1f, o1, 0, 0, 0); \
        lac = __builtin_amdgcn_mfma_f32_32x32x16_bf16(af_.v, ones, lac, 0, 0, 0); \
    }

    const int NT = SEQ / 128;                        // 16 iterations

    // prologue: stage tile 0 (128 k-rows) into buf 0
    {
        uint4 a0 = *(const uint4*)(gK);
        uint4 a1 = *(const uint4*)(gK + 8192);
        uint4 a2 = *(const uint4*)(gV);
        uint4 a3 = *(const uint4*)(gV + 131072);
        gK += 16384; gV += 256;
        char* lb = &ldsbuf[0][0];
        *(uint4*)(lb + dK)        = a0;
        *(uint4*)(lb + dK + 1024) = a1;
        *(uint4*)(lb + dV)        = a2;
        *(uint4*)(lb + dV + 512)  = a3;
    }
    __syncthreads();

    int cur = 0;
    for (int t = 0; t < NT; ++t) {
        const bool pf = (t + 1 < NT);
        uint4 a0, a1, a2, a3;
        if (pf) {
            a0 = *(const uint4*)(gK);
            a1 = *(const uint4*)(gK + 8192);
            a2 = *(const uint4*)(gV);
            a3 = *(const uint4*)(gV + 131072);
            gK += 16384; gV += 256;
        }
        const char* ldb = &ldsbuf[cur][0];
#pragma unroll
        for (int h = 0; h < 2; ++h) {
            const int kh = h * 1024, vh = h * 8192;
            f32x16 s0 = {}, s1 = {};
#pragma unroll
            for (int ks = 0; ks < 4; ++ks) {
                bf16x8 k0f = *(const bf16x8*)(ldb + kxo[ks] + kh);
                bf16x8 k1f = *(const bf16x8*)(ldb + kxo[ks] + kh + 512);
                s0 = __builtin_amdgcn_mfma_f32_32x32x16_bf16(k0f, qf[ks], s0, 0, 0, 0);
                s1 = __builtin_amdgcn_mfma_f32_32x32x16_bf16(k1f, qf[ks], s1, 0, 0, 0);
            }
            unsigned u0[8], u1[8];
#pragma unroll
            for (int m2 = 0; m2 < 8; ++m2) {
                u0[m2] = pk2(__builtin_amdgcn_exp2f(s0[2 * m2]),
                             __builtin_amdgcn_exp2f(s0[2 * m2 + 1]));
                u1[m2] = pk2(__builtin_amdgcn_exp2f(s1[2 * m2]),
                             __builtin_amdgcn_exp2f(s1[2 * m2 + 1]));
            }
            PV_STEP(u0, 0, 0, vh)
            PV_STEP(u0, 1, 1, vh)
            PV_STEP(u1, 0, 2, vh)
            PV_STEP(u1, 1, 3, vh)
        }
        if (pf) {
            char* lb = &ldsbuf[cur ^ 1][0];
            *(uint4*)(lb + dK)        = a0;
            *(uint4*)(lb + dK + 1024) = a1;
            *(uint4*)(lb + dV)        = a2;
            *(uint4*)(lb + dV + 512)  = a3;
        }
        __syncthreads();
        cur ^= 1;
    }
#undef PV_STEP

    // epilogue: lane holds O[q=qb+crow(r,hi)][d = nb*32 + l31]; lac[r] = denom
    const int b = bh >> 4, h = bh & 15;
#pragma unroll
    for (int r = 0; r < 16; ++r) {
        float inv = 1.0f / lac[r];
        int q = qb + (r & 3) + 8 * (r >> 2) + 4 * hi;
        size_t base = ((size_t)b * SEQ + q) * DIM + h * HD + l31;
        AO[base]      = (__bf16)(o0[r] * inv);
        AO[base + 32] = (__bf16)(o1[r] * inv);
    }
}

// ---------------- GEMM2: out = AO @ w_proj.T + b_proj (fp32 out) ----------
// R9-verified 2-barrier structure + T1 XCD swizzle: 1D grid 512, each XCD
// owns 8 contiguous m-panels (2MB A + 2MB W per XCD — L2-resident).
__global__ __launch_bounds__(256) void gemm_proj(
    const __bf16* __restrict__ A, const __bf16* __restrict__ W,
    const float* __restrict__ bias, float* __restrict__ out) {
    __shared__ __align__(16) __bf16 As[128][72];
    __shared__ __align__(16) __bf16 Bs[128][72];
    // 512 % 8 == 0 -> bijective.
    const int lin = blockIdx.x;
    const int swz = (lin & 7) * 64 + (lin >> 3);
    const int m0 = (swz / 8) * 128, n0 = (swz % 8) * 128;
    const int tid = threadIdx.x;
    const int w = tid >> 6, lane = tid & 63;
    const int wm = w >> 1, wn = w & 1;
    const int lr = lane & 15, lg = lane >> 4;
    const int ldr = tid >> 3;
    const int ldc = (tid & 7) * 8;

    f32x4 acc[4][4];
    const f32x4 z = {0.f, 0.f, 0.f, 0.f};
#pragma unroll
    for (int i = 0; i < 4; ++i)
#pragma unroll
        for (int j = 0; j < 4; ++j) acc[i][j] = z;

    for (int kt = 0; kt < DIM; kt += 64) {
#pragma unroll
        for (int rr = 0; rr < 128; rr += 32) {
            *(bf16x8*)&As[ldr + rr][ldc] =
                *(const bf16x8*)&A[(size_t)(m0 + ldr + rr) * DIM + kt + ldc];
            *(bf16x8*)&Bs[ldr + rr][ldc] =
                *(const bf16x8*)&W[(size_t)(n0 + ldr + rr) * DIM + kt + ldc];
        }
        __syncthreads();
#pragma unroll
        for (int kk = 0; kk < 2; ++kk) {
            bf16x8 a[4], b[4];
#pragma unroll
            for (int i = 0; i < 4; ++i)
                a[i] = *(const bf16x8*)&As[wm * 64 + i * 16 + lr][kk * 32 + lg * 8];
#pragma unroll
            for (int j = 0; j < 4; ++j)
                b[j] = *(const bf16x8*)&Bs[wn * 64 + j * 16 + lr][kk * 32 + lg * 8];
#pragma unroll
            for (int i = 0; i < 4; ++i)
#pragma unroll
                for (int j = 0; j < 4; ++j)
                    acc[i][j] = __builtin_amdgcn_mfma_f32_16x16x32_bf16(a[i], b[j], acc[i][j], 0, 0, 0);
        }
        __syncthreads();
    }

#pragma unroll
    for (int i = 0; i < 4; ++i) {
#pragma unroll
        for (int j = 0; j < 4; ++j) {
            int n = n0 + wn * 64 + j * 16 + lr;
            float bv = bias[n];
#pragma unroll
            for (int rr = 0; rr < 4; ++rr) {
                int m = m0 + wm * 64 + i * 16 + lg * 4 + rr;
                out[(size_t)m * DIM + n] = acc[i][j][rr] + bv;
            }
        }
    }
}

extern "C" void kernel_launch(void* const* d_in, const int* in_sizes, int n_in,
                              void* d_out, int out_size, void* d_ws, size_t ws_size,
                              hipStream_t stream) {
    const float* x    = (const float*)d_in[0];
    const float* wqkv = (const float*)d_in[1];
    const float* wproj= (const float*)d_in[2];
    const float* bproj= (const float*)d_in[3];
    float* out = (float*)d_out;

    __bf16* xb  = (__bf16*)d_ws;            // 8388608  (reused as AO later)
    __bf16* wqb = xb + NX;                  // 3145728
    __bf16* wpb = wqb + NQW;                // 1048576
    __bf16* Qb  = wpb + NPW;                // 8388608
    __bf16* Kb  = Qb + (size_t)NX;
    __bf16* Vtb = Kb + (size_t)NX;
    __bf16* AO  = xb;                       // alias: xb dead after gemm_qkv

    cvt_all<<<2048, 256, 0, stream>>>(x, wqkv, wproj, xb, wqb, wpb);
    gemm_qkv<<<1536, 256, 0, stream>>>(xb, wqb, Qb, Kb, Vtb);
    flash_attn10<<<512, 512, 0, stream>>>(Qb, Kb, Vtb, AO);
    gemm_proj<<<512, 256, 0, stream>>>(AO, wpb, bproj, out);
}

// Round 17
// 189.134 us; speedup vs baseline: 1.0017x; 1.0017x over previous
//
#include <hip/hip_runtime.h>
#include <hip/hip_bf16.h>

typedef __bf16 bf16x8 __attribute__((ext_vector_type(8)));
typedef __bf16 bf16x4 __attribute__((ext_vector_type(4)));
typedef float  f32x4  __attribute__((ext_vector_type(4)));
typedef float  f32x16 __attribute__((ext_vector_type(16)));

#define DIM 1024
#define NHEAD 16
#define HD 64
#define BATCH 4
#define SEQ 2048
#define MROWS (BATCH * SEQ)        // 8192
#define NX (MROWS * DIM)           // 8388608
#define NQW (3 * DIM * DIM)        // 3145728
#define NPW (DIM * DIM)            // 1048576

// Q pre-scale: (1/sqrt(64)) * log2(e), so softmax uses exp2 directly.
#define QSC (0.125f * 1.44269504088896340736f)

// ---------------- fp32 -> bf16 convert (all three tensors, one launch) ----
__global__ void cvt_all(const float* __restrict__ x, const float* __restrict__ wq,
                        const float* __restrict__ wp, __bf16* __restrict__ xb,
                        __bf16* __restrict__ wqb, __bf16* __restrict__ wpb) {
    const int total = (NX + NQW + NPW) / 4;
    int stride = gridDim.x * blockDim.x;
    for (int c = blockIdx.x * blockDim.x + threadIdx.x; c < total; c += stride) {
        int i = c * 4;
        const float* src; __bf16* dst; int off;
        if (i < NX)            { src = x;  dst = xb;  off = i; }
        else if (i < NX + NQW) { src = wq; dst = wqb; off = i - NX; }
        else                   { src = wp; dst = wpb; off = i - NX - NQW; }
        float4 v = *(const float4*)&src[off];
        bf16x4 o = { (__bf16)v.x, (__bf16)v.y, (__bf16)v.z, (__bf16)v.w };
        *(bf16x4*)&dst[off] = o;
    }
}

// ---------------- GEMM1: qkv = x @ w_qkv.T, scatter to Q/K/Vt -------------
// R9-verified 2-barrier structure + T1 XCD swizzle: 1D grid 1536, each XCD
// owns 8 contiguous m-panels (A L2-resident: 2MB A + 6MB W per XCD).
__global__ __launch_bounds__(256) void gemm_qkv(
    const __bf16* __restrict__ X, const __bf16* __restrict__ W,
    __bf16* __restrict__ Qo, __bf16* __restrict__ Ko, __bf16* __restrict__ Vt) {
    __shared__ __align__(16) __bf16 As[128][72];
    __shared__ __align__(16) __bf16 Bs[128][72];
    // XCD swizzle: hw XCD = lin%8; XCD x gets swz in [x*192, (x+1)*192) ->
    // m-panels [x*8, x*8+8), n fast. 1536 % 8 == 0 -> bijective.
    const int lin = blockIdx.x;
    const int swz = (lin & 7) * 192 + (lin >> 3);
    const int m0 = (swz / 24) * 128, n0 = (swz % 24) * 128;
    const int tid = threadIdx.x;
    const int w = tid >> 6, lane = tid & 63;
    const int wm = w >> 1, wn = w & 1;
    const int lr = lane & 15, lg = lane >> 4;
    const int ldr = tid >> 3;          // 0..31
    const int ldc = (tid & 7) * 8;     // 0..56

    f32x4 acc[4][4];
    const f32x4 z = {0.f, 0.f, 0.f, 0.f};
#pragma unroll
    for (int i = 0; i < 4; ++i)
#pragma unroll
        for (int j = 0; j < 4; ++j) acc[i][j] = z;

    for (int kt = 0; kt < DIM; kt += 64) {
#pragma unroll
        for (int rr = 0; rr < 128; rr += 32) {
            *(bf16x8*)&As[ldr + rr][ldc] =
                *(const bf16x8*)&X[(size_t)(m0 + ldr + rr) * DIM + kt + ldc];
            *(bf16x8*)&Bs[ldr + rr][ldc] =
                *(const bf16x8*)&W[(size_t)(n0 + ldr + rr) * DIM + kt + ldc];
        }
        __syncthreads();
#pragma unroll
        for (int kk = 0; kk < 2; ++kk) {
            bf16x8 a[4], b[4];
#pragma unroll
            for (int i = 0; i < 4; ++i)
                a[i] = *(const bf16x8*)&As[wm * 64 + i * 16 + lr][kk * 32 + lg * 8];
#pragma unroll
            for (int j = 0; j < 4; ++j)
                b[j] = *(const bf16x8*)&Bs[wn * 64 + j * 16 + lr][kk * 32 + lg * 8];
#pragma unroll
            for (int i = 0; i < 4; ++i)
#pragma unroll
                for (int j = 0; j < 4; ++j)
                    acc[i][j] = __builtin_amdgcn_mfma_f32_16x16x32_bf16(a[i], b[j], acc[i][j], 0, 0, 0);
        }
        __syncthreads();
    }

    // epilogue: n -> (t, h, d); t uniform per block (128 | 1024)
    const int t = n0 >> 10;
    if (t < 2) {
        __bf16* dst = (t == 0) ? Qo : Ko;
        const float sc = (t == 0) ? QSC : 1.0f;
#pragma unroll
        for (int i = 0; i < 4; ++i) {
#pragma unroll
            for (int j = 0; j < 4; ++j) {
                int n = n0 + wn * 64 + j * 16 + lr;
                int rem = n & 1023, h = rem >> 6, d = rem & 63;
#pragma unroll
                for (int rr = 0; rr < 4; ++rr) {
                    int m = m0 + wm * 64 + i * 16 + lg * 4 + rr;
                    int b = m >> 11, pos = m & 2047;
                    dst[(((size_t)b * NHEAD + h) * SEQ + pos) * HD + d] =
                        (__bf16)(acc[i][j][rr] * sc);
                }
            }
        }
    } else {
        // V: transposed store, vectorized bf16x4 (rr -> consecutive pos)
#pragma unroll
        for (int i = 0; i < 4; ++i) {
#pragma unroll
            for (int j = 0; j < 4; ++j) {
                int n = n0 + wn * 64 + j * 16 + lr;
                int rem = n & 1023, h = rem >> 6, d = rem & 63;
                int m = m0 + wm * 64 + i * 16 + lg * 4;
                int b = m >> 11, pos = m & 2047;
                bf16x4 v4 = { (__bf16)acc[i][j][0], (__bf16)acc[i][j][1],
                              (__bf16)acc[i][j][2], (__bf16)acc[i][j][3] };
                *(bf16x4*)&Vt[(((size_t)b * NHEAD + h) * HD + d) * SEQ + pos] = v4;
            }
        }
    }
}

// pack two f32 -> one u32 of 2 bf16 (lo = a, hi = b); scalar casts — the
// compiler fuses these to v_cvt_pk_bf16_f32 itself (T12/m240).
__device__ __forceinline__ unsigned pk2(float a, float b) {
    __bf16 x = (__bf16)a, y = (__bf16)b;
    unsigned short xu = __builtin_bit_cast(unsigned short, x);
    unsigned short yu = __builtin_bit_cast(unsigned short, y);
    return (unsigned)xu | ((unsigned)yu << 16);
}

// ---------------- flash attention, KVBLK=128 LDS-staged K/V ---------------
// (R12/R13/R15 triple-verified at 88.2-88.4 µs: 512 blocks XCD-swizzled,
// 8 waves x 32 q-rows, 128 k-rows staged per barrier — two 64-row compute
// halves per iteration, 16 iterations, 1 barrier each. Double-buffered
// 32KB buffers. DO NOT reorder the inner loop: a semantically identical
// reorder (R16) mis-executed — the permlane-asm/MFMA pattern is
// scheduling-sensitive; this exact source compiles to a verified schedule.)
// LDS layout per buffer (16B chunks):
//   K region [0,16384):     chunk(sub,row) at sub*2048 + (row*16 ^ sub*16),
//                           sub = d-octet 0..7, row 0..127
//   V region [16384,32768): chunk(j,d) at 16384 + j*1024 + (d*16 ^ (j&7)*16),
//                           j = k-octet 0..15, d 0..63
// XOR applied identically on write and read (bijective per region).
__global__ __launch_bounds__(512) void flash_attn10(
    const __bf16* __restrict__ Q, const __bf16* __restrict__ K,
    const __bf16* __restrict__ Vt, __bf16* __restrict__ AO) {
    __shared__ __align__(16) char ldsbuf[2][32768];
    const int L = blockIdx.x;                 // 0..511
    const int xcd = L & 7;                    // hw XCD = id % 8
    const int mloc = L >> 3;                  // 0..63 within XCD
    const int bh = xcd * 8 + (mloc >> 3);     // 8 heads per XCD
    const int qt = mloc & 7;                  // q-tile (256 rows), fast index
    const int tid = threadIdx.x;              // 0..511
    const int w = tid >> 6, lane = tid & 63;  // w: 0..7
    const int l31 = lane & 31, hi = lane >> 5;
    const int qb = qt * 256 + w * 32;
    const size_t kvQ = (size_t)bh * SEQ * HD;
    const size_t kvV = (size_t)bh * HD * SEQ;

    // Q B-frags: qf[ks][j] = Q[qb + l31][ks*16 + hi*8 + j]  (one-time gather)
    bf16x8 qf[4];
#pragma unroll
    for (int ks = 0; ks < 4; ++ks)
        qf[ks] = *(const bf16x8*)&Q[kvQ + (size_t)(qb + l31) * HD + ks * 16 + hi * 8];

    bf16x8 ones;
#pragma unroll
    for (int j = 0; j < 8; ++j) ones[j] = (__bf16)1.0f;

    f32x16 o0 = {}, o1 = {}, lac = {};

    const char* gK = (const char*)K + kvQ * 2 + tid * 16;
    const char* gV = (const char*)Vt + kvV * 2 + (size_t)(tid >> 4) * 4096 + (tid & 15) * 16;
    const int dK = (tid & 7) * 2048 + (((tid >> 3) * 16) ^ ((tid & 7) * 16));
    const int dV = 16384 + (tid & 15) * 1024 + (((tid >> 4) * 16) ^ (((tid & 15) & 7) * 16));

    int kxo[4], vxo[4];
#pragma unroll
    for (int i = 0; i < 4; ++i) {
        kxo[i] = i * 4096 + hi * 2048 + ((l31 * 16) ^ ((2 * i + hi) << 4));
        vxo[i] = 16384 + i * 2048 + hi * 1024 + ((l31 * 16) ^ ((2 * i + hi) << 4));
    }

#define PV_STEP(UARR, C, CT, VH)                                                \
    {                                                                           \
        unsigned w0_ = UARR[4 * C], w1_ = UARR[4 * C + 1];                      \
        unsigned w2_ = UARR[4 * C + 2], w3_ = UARR[4 * C + 3];                  \
        asm("v_permlane32_swap_b32 %0, %1" : "+v"(w0_), "+v"(w2_));             \
        asm("v_permlane32_swap_b32 %0, %1" : "+v"(w1_), "+v"(w3_));             \
        union { unsigned q[4]; bf16x8 v; } af_;                                 \
        af_.q[0] = w0_; af_.q[1] = w1_; af_.q[2] = w2_; af_.q[3] = w3_;         \
        bf16x8 v0f = *(const bf16x8*)(ldb + vxo[CT] + (VH));                    \
        bf16x8 v1f = *(const bf16x8*)(ldb + vxo[CT] + (VH) + 512);              \
        o0  = __builtin_amdgcn_mfma_f32_32x32x16_bf16(af_.v, v0f, o0, 0, 0, 0); \
        o1  = __builtin_amdgcn_mfma_f32_32x32x16_bf16(af_.v, v1f, o1, 0, 0, 0); \
        lac = __builtin_amdgcn_mfma_f32_32x32x16_bf16(af_.v, ones, lac, 0, 0, 0); \
    }

    const int NT = SEQ / 128;                        // 16 iterations

    // prologue: stage tile 0 (128 k-rows) into buf 0
    {
        uint4 a0 = *(const uint4*)(gK);
        uint4 a1 = *(const uint4*)(gK + 8192);
        uint4 a2 = *(const uint4*)(gV);
        uint4 a3 = *(const uint4*)(gV + 131072);
        gK += 16384; gV += 256;
        char* lb = &ldsbuf[0][0];
        *(uint4*)(lb + dK)        = a0;
        *(uint4*)(lb + dK + 1024) = a1;
        *(uint4*)(lb + dV)        = a2;
        *(uint4*)(lb + dV + 512)  = a3;
    }
    __syncthreads();

    int cur = 0;
    for (int t = 0; t < NT; ++t) {
        const bool pf = (t + 1 < NT);
        uint4 a0, a1, a2, a3;
        if (pf) {
            a0 = *(const uint4*)(gK);
            a1 = *(const uint4*)(gK + 8192);
            a2 = *(const uint4*)(gV);
            a3 = *(const uint4*)(gV + 131072);
            gK += 16384; gV += 256;
        }
        const char* ldb = &ldsbuf[cur][0];
#pragma unroll
        for (int h = 0; h < 2; ++h) {
            const int kh = h * 1024, vh = h * 8192;
            f32x16 s0 = {}, s1 = {};
#pragma unroll
            for (int ks = 0; ks < 4; ++ks) {
                bf16x8 k0f = *(const bf16x8*)(ldb + kxo[ks] + kh);
                bf16x8 k1f = *(const bf16x8*)(ldb + kxo[ks] + kh + 512);
                s0 = __builtin_amdgcn_mfma_f32_32x32x16_bf16(k0f, qf[ks], s0, 0, 0, 0);
                s1 = __builtin_amdgcn_mfma_f32_32x32x16_bf16(k1f, qf[ks], s1, 0, 0, 0);
            }
            unsigned u0[8], u1[8];
#pragma unroll
            for (int m2 = 0; m2 < 8; ++m2) {
                u0[m2] = pk2(__builtin_amdgcn_exp2f(s0[2 * m2]),
                             __builtin_amdgcn_exp2f(s0[2 * m2 + 1]));
                u1[m2] = pk2(__builtin_amdgcn_exp2f(s1[2 * m2]),
                             __builtin_amdgcn_exp2f(s1[2 * m2 + 1]));
            }
            PV_STEP(u0, 0, 0, vh)
            PV_STEP(u0, 1, 1, vh)
            PV_STEP(u1, 0, 2, vh)
            PV_STEP(u1, 1, 3, vh)
        }
        if (pf) {
            char* lb = &ldsbuf[cur ^ 1][0];
            *(uint4*)(lb + dK)        = a0;
            *(uint4*)(lb + dK + 1024) = a1;
            *(uint4*)(lb + dV)        = a2;
            *(uint4*)(lb + dV + 512)  = a3;
        }
        __syncthreads();
        cur ^= 1;
    }
#undef PV_STEP

    // epilogue: lane holds O[q=qb+crow(r,hi)][d = nb*32 + l31]; lac[r] = denom
    const int b = bh >> 4, h = bh & 15;
#pragma unroll
    for (int r = 0; r < 16; ++r) {
        float inv = 1.0f / lac[r];
        int q = qb + (r & 3) + 8 * (r >> 2) + 4 * hi;
        size_t base = ((size_t)b * SEQ + q) * DIM + h * HD + l31;
        AO[base]      = (__bf16)(o0[r] * inv);
        AO[base + 32] = (__bf16)(o1[r] * inv);
    }
}

// ---------------- GEMM2: out = AO @ w_proj.T + b_proj (fp32 out) ----------
// R9-verified 2-barrier structure + T1 XCD swizzle: 1D grid 512, each XCD
// owns 8 contiguous m-panels (2MB A + 2MB W per XCD — L2-resident).
__global__ __launch_bounds__(256) void gemm_proj(
    const __bf16* __restrict__ A, const __bf16* __restrict__ W,
    const float* __restrict__ bias, float* __restrict__ out) {
    __shared__ __align__(16) __bf16 As[128][72];
    __shared__ __align__(16) __bf16 Bs[128][72];
    // 512 % 8 == 0 -> bijective.
    const int lin = blockIdx.x;
    const int swz = (lin & 7) * 64 + (lin >> 3);
    const int m0 = (swz / 8) * 128, n0 = (swz % 8) * 128;
    const int tid = threadIdx.x;
    const int w = tid >> 6, lane = tid & 63;
    const int wm = w >> 1, wn = w & 1;
    const int lr = lane & 15, lg = lane >> 4;
    const int ldr = tid >> 3;
    const int ldc = (tid & 7) * 8;

    f32x4 acc[4][4];
    const f32x4 z = {0.f, 0.f, 0.f, 0.f};
#pragma unroll
    for (int i = 0; i < 4; ++i)
#pragma unroll
        for (int j = 0; j < 4; ++j) acc[i][j] = z;

    for (int kt = 0; kt < DIM; kt += 64) {
#pragma unroll
        for (int rr = 0; rr < 128; rr += 32) {
            *(bf16x8*)&As[ldr + rr][ldc] =
                *(const bf16x8*)&A[(size_t)(m0 + ldr + rr) * DIM + kt + ldc];
            *(bf16x8*)&Bs[ldr + rr][ldc] =
                *(const bf16x8*)&W[(size_t)(n0 + ldr + rr) * DIM + kt + ldc];
        }
        __syncthreads();
#pragma unroll
        for (int kk = 0; kk < 2; ++kk) {
            bf16x8 a[4], b[4];
#pragma unroll
            for (int i = 0; i < 4; ++i)
                a[i] = *(const bf16x8*)&As[wm * 64 + i * 16 + lr][kk * 32 + lg * 8];
#pragma unroll
            for (int j = 0; j < 4; ++j)
                b[j] = *(const bf16x8*)&Bs[wn * 64 + j * 16 + lr][kk * 32 + lg * 8];
#pragma unroll
            for (int i = 0; i < 4; ++i)
#pragma unroll
                for (int j = 0; j < 4; ++j)
                    acc[i][j] = __builtin_amdgcn_mfma_f32_16x16x32_bf16(a[i], b[j], acc[i][j], 0, 0, 0);
        }
        __syncthreads();
    }

#pragma unroll
    for (int i = 0; i < 4; ++i) {
#pragma unroll
        for (int j = 0; j < 4; ++j) {
            int n = n0 + wn * 64 + j * 16 + lr;
            float bv = bias[n];
#pragma unroll
            for (int rr = 0; rr < 4; ++rr) {
                int m = m0 + wm * 64 + i * 16 + lg * 4 + rr;
                out[(size_t)m * DIM + n] = acc[i][j][rr] + bv;
            }
        }
    }
}

extern "C" void kernel_launch(void* const* d_in, const int* in_sizes, int n_in,
                              void* d_out, int out_size, void* d_ws, size_t ws_size,
                              hipStream_t stream) {
    const float* x    = (const float*)d_in[0];
    const float* wqkv = (const float*)d_in[1];
    const float* wproj= (const float*)d_in[2];
    const float* bproj= (const float*)d_in[3];
    float* out = (float*)d_out;

    __bf16* xb  = (__bf16*)d_ws;            // 8388608  (reused as AO later)
    __bf16* wqb = xb + NX;                  // 3145728
    __bf16* wpb = wqb + NQW;                // 1048576
    __bf16* Qb  = wpb + NPW;                // 8388608
    __bf16* Kb  = Qb + (size_t)NX;
    __bf16* Vtb = Kb + (size_t)NX;
    __bf16* AO  = xb;                       // alias: xb dead after gemm_qkv

    cvt_all<<<2048, 256, 0, stream>>>(x, wqkv, wproj, xb, wqb, wpb);
    gemm_qkv<<<1536, 256, 0, stream>>>(xb, wqb, Qb, Kb, Vtb);
    flash_attn10<<<512, 512, 0, stream>>>(Qb, Kb, Vtb, AO);
    gemm_proj<<<512, 256, 0, stream>>>(AO, wpb, bproj, out);
}